// Round 4
// baseline (269.020 us; speedup 1.0000x reference)
//
#include <hip/hip_runtime.h>
#include <math.h>

// Time2Vec: out[b,l,d,e] = (e==0) ? x[b,l,d]*W[d,0]+b[d,0]
//                                 : sin(x[b,l,d]*W[d,e]+b[d,e])
// B=32 L=4096 D=8 E=64. Output 256 MiB fp32 -> write-BW-bound.
// Timed region includes harness poison fills (~212 us fixed);
// kernel floor: 268 MB / 6.3 TB/s ~= 42 us.
//
// Key simplification: each thread's (W,b) float4 index is t & 127 --
// a pure function of threadIdx -- so no LDS staging and NO BARRIER.
// W/b (4 KiB total) are L2-resident after the first blocks.

typedef float fx4 __attribute__((ext_vector_type(4)));

__global__ __launch_bounds__(256) void t2v_kernel(
    const float* __restrict__ x,    // B*L*D
    const float* __restrict__ W,    // 512
    const float* __restrict__ bias, // 512
    fx4* __restrict__ out)          // B*L*D*E / 4 float4s
{
    const int t = threadIdx.x;
    // Each block covers 2048 consecutive float4s: 8 per thread, stride 256.
    // wi = (blk*2048 + t + k*256) & 127 == t & 127 for all k.
    const int wi = t & 127;
    const float4 w = ((const float4*)W)[wi];
    const float4 c = ((const float4*)bias)[wi];

    const int base = blockIdx.x * 2048 + t;

#pragma unroll
    for (int k = 0; k < 8; ++k) {
        const int i = base + k * 256;         // float4 index
        const float xv = x[i >> 4];           // 16 float4s per x element
        float ax = fmaf(xv, w.x, c.x);
        float ay = fmaf(xv, w.y, c.y);
        float az = fmaf(xv, w.z, c.z);
        float aw = fmaf(xv, w.w, c.w);
        fx4 o;
        o.x = ((i & 15) == 0) ? ax : __sinf(ax);  // e==0 only at i%16==0, lane .x
        o.y = __sinf(ay);
        o.z = __sinf(az);
        o.w = __sinf(aw);
        __builtin_nontemporal_store(o, &out[i]);
    }
}

extern "C" void kernel_launch(void* const* d_in, const int* in_sizes, int n_in,
                              void* d_out, int out_size, void* d_ws, size_t ws_size,
                              hipStream_t stream) {
    const float* x    = (const float*)d_in[0];
    const float* W    = (const float*)d_in[1];
    const float* bias = (const float*)d_in[2];
    fx4* out = (fx4*)d_out;

    // out_size = 67108864 floats = 16777216 float4 = 8192 blocks * 2048
    const int blocks = (out_size >> 2) / 2048;
    t2v_kernel<<<blocks, 256, 0, stream>>>(x, W, bias, out);
}